// Round 1
// baseline (613.548 us; speedup 1.0000x reference)
//
#include <hip/hip_runtime.h>

#define N_NODES 50000
#define N_EDGES 500000
#define D 256
#define TWO_D 512

typedef __attribute__((ext_vector_type(8))) __bf16 bf16x8;
typedef __attribute__((ext_vector_type(4))) float f32x4;
typedef unsigned short ushort_t;

__device__ __forceinline__ unsigned short f2bf(float f) {
    unsigned int u = __builtin_bit_cast(unsigned int, f);
    u += 0x7FFFu + ((u >> 16) & 1u);   // round-to-nearest-even
    return (unsigned short)(u >> 16);
}
__device__ __forceinline__ unsigned int pk2(float lo, float hi) {
    return (unsigned int)f2bf(lo) | ((unsigned int)f2bf(hi) << 16);
}

// ---------------- prep kernels ----------------

__global__ void k_zero(float* __restrict__ p, int n4) {
    int i = blockIdx.x * blockDim.x + threadIdx.x;
    if (i < n4) ((float4*)p)[i] = make_float4(0.f, 0.f, 0.f, 0.f);
}

__global__ void k_cvt_x(const float* __restrict__ x, ushort_t* __restrict__ xb, int n8) {
    int i = blockIdx.x * blockDim.x + threadIdx.x;
    if (i < n8) {
        const float4* s = (const float4*)(x + (size_t)i * 8);
        float4 a = s[0], b = s[1];
        uint4 o;
        o.x = pk2(a.x, a.y); o.y = pk2(a.z, a.w);
        o.z = pk2(b.x, b.y); o.w = pk2(b.z, b.w);
        *(uint4*)(xb + (size_t)i * 8) = o;
    }
}

// W [TWO_D][D] f32  ->  Wt [D][TWO_D] bf16
__global__ void k_wt(const float* __restrict__ w, ushort_t* __restrict__ wt) {
    int n = blockIdx.x;
    for (int k = threadIdx.x; k < TWO_D; k += blockDim.x)
        wt[(size_t)n * TWO_D + k] = f2bf(w[(size_t)k * D + n]);
}

__global__ void k_count(const int* __restrict__ coli, float* __restrict__ cnt) {
    int e = blockIdx.x * blockDim.x + threadIdx.x;
    if (e < N_EDGES) atomicAdd(&cnt[coli[e]], 1.0f);
}

// ---------------- edge GEMM + scatter ----------------
// C[e][n] = relu( concat(x[row[e]], ea[e]) @ W1 + b1 ); atomicAdd into agg[col[e]]
__global__ __launch_bounds__(256) void k_edge(
    const ushort_t* __restrict__ xb, const float* __restrict__ ea,
    const ushort_t* __restrict__ w1t, const float* __restrict__ b1,
    const int* __restrict__ rowi, const int* __restrict__ coli,
    float* __restrict__ agg)
{
    __shared__ __align__(16) ushort_t As[64 * 64];
    __shared__ __align__(16) ushort_t Bs[256 * 64];
    const int tid = threadIdx.x;
    const int wave = tid >> 6, lane = tid & 63;
    const int lr = lane & 15, lh = lane >> 4;
    const int e0 = blockIdx.x * 64;

    // staging coords: 4 threads per A row, 16 cols each
    const int sm = tid >> 2;
    const int sc = (tid & 3) << 4;
    int es = e0 + sm; if (es >= N_EDGES) es = N_EDGES - 1;
    const int srow = rowi[es];
    const ushort_t* xrow  = xb + (size_t)srow * D;
    const float*    earow = ea + (size_t)es * D;
    const ushort_t* wrow  = w1t + (size_t)tid * TWO_D;
    const int swA = (sm & 7) << 3;
    const int swB = (tid & 7) << 3;

    f32x4 acc[4][4];
    #pragma unroll
    for (int i = 0; i < 4; ++i)
        #pragma unroll
        for (int j = 0; j < 4; ++j)
            acc[i][j] = (f32x4){0.f, 0.f, 0.f, 0.f};

    for (int kk = 0; kk < 8; ++kk) {
        const int k0 = kk << 6;
        uint4 av0, av1;
        if (kk < 4) {
            const uint4* s = (const uint4*)(xrow + k0 + sc);
            av0 = s[0]; av1 = s[1];
        } else {
            const float4* s = (const float4*)(earow + (k0 - D) + sc);
            float4 f0 = s[0], f1 = s[1], f2 = s[2], f3 = s[3];
            av0.x = pk2(f0.x, f0.y); av0.y = pk2(f0.z, f0.w);
            av0.z = pk2(f1.x, f1.y); av0.w = pk2(f1.z, f1.w);
            av1.x = pk2(f2.x, f2.y); av1.y = pk2(f2.z, f2.w);
            av1.z = pk2(f3.x, f3.y); av1.w = pk2(f3.z, f3.w);
        }
        const uint4* wsv = (const uint4*)(wrow + k0);
        uint4 w0 = wsv[0], w1 = wsv[1], w2 = wsv[2], w3 = wsv[3];
        uint4 w4 = wsv[4], w5 = wsv[5], w6 = wsv[6], w7 = wsv[7];

        __syncthreads();   // previous iteration's reads done
        *(uint4*)&As[sm * 64 + ( sc      ^ swA)] = av0;
        *(uint4*)&As[sm * 64 + ((sc + 8) ^ swA)] = av1;
        {
            const int base = tid * 64;
            *(uint4*)&Bs[base + ( 0 ^ swB)] = w0;
            *(uint4*)&Bs[base + ( 8 ^ swB)] = w1;
            *(uint4*)&Bs[base + (16 ^ swB)] = w2;
            *(uint4*)&Bs[base + (24 ^ swB)] = w3;
            *(uint4*)&Bs[base + (32 ^ swB)] = w4;
            *(uint4*)&Bs[base + (40 ^ swB)] = w5;
            *(uint4*)&Bs[base + (48 ^ swB)] = w6;
            *(uint4*)&Bs[base + (56 ^ swB)] = w7;
        }
        __syncthreads();

        #pragma unroll
        for (int kh = 0; kh < 2; ++kh) {
            const int kb = kh * 32 + lh * 8;
            bf16x8 af[4], bfr[4];
            #pragma unroll
            for (int i = 0; i < 4; ++i) {
                int m = i * 16 + lr;
                af[i] = *(const bf16x8*)&As[m * 64 + (kb ^ ((m & 7) << 3))];
            }
            #pragma unroll
            for (int j = 0; j < 4; ++j) {
                int n = wave * 64 + j * 16 + lr;
                bfr[j] = *(const bf16x8*)&Bs[n * 64 + (kb ^ ((n & 7) << 3))];
            }
            #pragma unroll
            for (int i = 0; i < 4; ++i)
                #pragma unroll
                for (int j = 0; j < 4; ++j)
                    acc[i][j] = __builtin_amdgcn_mfma_f32_16x16x32_bf16(af[i], bfr[j], acc[i][j], 0, 0, 0);
        }
    }

    // epilogue: bias + relu + atomic scatter-add (skip zeros)
    float bv[4];
    #pragma unroll
    for (int j = 0; j < 4; ++j) bv[j] = b1[wave * 64 + j * 16 + lr];
    #pragma unroll
    for (int i = 0; i < 4; ++i) {
        #pragma unroll
        for (int r = 0; r < 4; ++r) {
            int m = i * 16 + lh * 4 + r;
            int e = e0 + m;
            if (e < N_EDGES) {
                float* arow = agg + (size_t)coli[e] * D;
                #pragma unroll
                for (int j = 0; j < 4; ++j) {
                    float v = acc[i][j][r] + bv[j];
                    if (v > 0.f) atomicAdd(&arow[wave * 64 + j * 16 + lr], v);
                }
            }
        }
    }
}

// ---------------- node GEMM ----------------
// out[i][n] = relu( concat(x[i], agg[i]/max(cnt,1)) @ W2 + b2 )
__global__ __launch_bounds__(256) void k_node(
    const ushort_t* __restrict__ xb, const float* __restrict__ agg,
    const float* __restrict__ cnt,
    const ushort_t* __restrict__ w2t, const float* __restrict__ b2,
    float* __restrict__ out)
{
    __shared__ __align__(16) ushort_t As[64 * 64];
    __shared__ __align__(16) ushort_t Bs[256 * 64];
    const int tid = threadIdx.x;
    const int wave = tid >> 6, lane = tid & 63;
    const int lr = lane & 15, lh = lane >> 4;
    const int n0 = blockIdx.x * 64;

    const int sm = tid >> 2;
    const int sc = (tid & 3) << 4;
    int ns = n0 + sm; if (ns >= N_NODES) ns = N_NODES - 1;
    const ushort_t* xrow = xb  + (size_t)ns * D;
    const float*    arow = agg + (size_t)ns * D;
    const float     ic   = 1.0f / fmaxf(cnt[ns], 1.0f);
    const ushort_t* wrow = w2t + (size_t)tid * TWO_D;
    const int swA = (sm & 7) << 3;
    const int swB = (tid & 7) << 3;

    f32x4 acc[4][4];
    #pragma unroll
    for (int i = 0; i < 4; ++i)
        #pragma unroll
        for (int j = 0; j < 4; ++j)
            acc[i][j] = (f32x4){0.f, 0.f, 0.f, 0.f};

    for (int kk = 0; kk < 8; ++kk) {
        const int k0 = kk << 6;
        uint4 av0, av1;
        if (kk < 4) {
            const uint4* s = (const uint4*)(xrow + k0 + sc);
            av0 = s[0]; av1 = s[1];
        } else {
            const float4* s = (const float4*)(arow + (k0 - D) + sc);
            float4 f0 = s[0], f1 = s[1], f2 = s[2], f3 = s[3];
            f0.x *= ic; f0.y *= ic; f0.z *= ic; f0.w *= ic;
            f1.x *= ic; f1.y *= ic; f1.z *= ic; f1.w *= ic;
            f2.x *= ic; f2.y *= ic; f2.z *= ic; f2.w *= ic;
            f3.x *= ic; f3.y *= ic; f3.z *= ic; f3.w *= ic;
            av0.x = pk2(f0.x, f0.y); av0.y = pk2(f0.z, f0.w);
            av0.z = pk2(f1.x, f1.y); av0.w = pk2(f1.z, f1.w);
            av1.x = pk2(f2.x, f2.y); av1.y = pk2(f2.z, f2.w);
            av1.z = pk2(f3.x, f3.y); av1.w = pk2(f3.z, f3.w);
        }
        const uint4* wsv = (const uint4*)(wrow + k0);
        uint4 w0 = wsv[0], w1 = wsv[1], w2 = wsv[2], w3 = wsv[3];
        uint4 w4 = wsv[4], w5 = wsv[5], w6 = wsv[6], w7 = wsv[7];

        __syncthreads();
        *(uint4*)&As[sm * 64 + ( sc      ^ swA)] = av0;
        *(uint4*)&As[sm * 64 + ((sc + 8) ^ swA)] = av1;
        {
            const int base = tid * 64;
            *(uint4*)&Bs[base + ( 0 ^ swB)] = w0;
            *(uint4*)&Bs[base + ( 8 ^ swB)] = w1;
            *(uint4*)&Bs[base + (16 ^ swB)] = w2;
            *(uint4*)&Bs[base + (24 ^ swB)] = w3;
            *(uint4*)&Bs[base + (32 ^ swB)] = w4;
            *(uint4*)&Bs[base + (40 ^ swB)] = w5;
            *(uint4*)&Bs[base + (48 ^ swB)] = w6;
            *(uint4*)&Bs[base + (56 ^ swB)] = w7;
        }
        __syncthreads();

        #pragma unroll
        for (int kh = 0; kh < 2; ++kh) {
            const int kb = kh * 32 + lh * 8;
            bf16x8 af[4], bfr[4];
            #pragma unroll
            for (int i = 0; i < 4; ++i) {
                int m = i * 16 + lr;
                af[i] = *(const bf16x8*)&As[m * 64 + (kb ^ ((m & 7) << 3))];
            }
            #pragma unroll
            for (int j = 0; j < 4; ++j) {
                int n = wave * 64 + j * 16 + lr;
                bfr[j] = *(const bf16x8*)&Bs[n * 64 + (kb ^ ((n & 7) << 3))];
            }
            #pragma unroll
            for (int i = 0; i < 4; ++i)
                #pragma unroll
                for (int j = 0; j < 4; ++j)
                    acc[i][j] = __builtin_amdgcn_mfma_f32_16x16x32_bf16(af[i], bfr[j], acc[i][j], 0, 0, 0);
        }
    }

    float bv[4];
    #pragma unroll
    for (int j = 0; j < 4; ++j) bv[j] = b2[wave * 64 + j * 16 + lr];
    #pragma unroll
    for (int i = 0; i < 4; ++i) {
        #pragma unroll
        for (int r = 0; r < 4; ++r) {
            int m = i * 16 + lh * 4 + r;
            int node = n0 + m;
            if (node < N_NODES) {
                float* orow = out + (size_t)node * D;
                #pragma unroll
                for (int j = 0; j < 4; ++j) {
                    float v = acc[i][j][r] + bv[j];
                    orow[wave * 64 + j * 16 + lr] = v > 0.f ? v : 0.f;
                }
            }
        }
    }
}

// ---------------- launch ----------------

extern "C" void kernel_launch(void* const* d_in, const int* in_sizes, int n_in,
                              void* d_out, int out_size, void* d_ws, size_t ws_size,
                              hipStream_t stream)
{
    const float* x  = (const float*)d_in[0];
    const int*   ei = (const int*)d_in[1];      // [2*E] int32: rows then cols
    const float* ea = (const float*)d_in[2];
    // d_in[3] = u (unused), d_in[4] = batch (unused)
    const float* W1 = (const float*)d_in[5];
    const float* b1 = (const float*)d_in[6];
    const float* W2 = (const float*)d_in[7];
    const float* b2 = (const float*)d_in[8];
    float* out = (float*)d_out;

    const int* rowi = ei;
    const int* coli = ei + N_EDGES;

    // workspace layout
    float* agg = (float*)d_ws;                              // N*D f32      (51.2 MB)
    float* cnt = agg + (size_t)N_NODES * D;                 // 50000 f32 (pad to 50048)
    ushort_t* xb  = (ushort_t*)(cnt + 50048);               // N*D bf16     (25.6 MB)
    ushort_t* w1t = xb + (size_t)N_NODES * D;               // D*TWO_D bf16
    ushort_t* w2t = w1t + (size_t)D * TWO_D;                // D*TWO_D bf16

    const int zf4 = (N_NODES * D + 50048) / 4;              // float4 count
    k_zero <<<(zf4 + 255) / 256, 256, 0, stream>>>(agg, zf4);
    k_cvt_x<<<(N_NODES * D / 8 + 255) / 256, 256, 0, stream>>>(x, xb, N_NODES * D / 8);
    k_wt   <<<D, 256, 0, stream>>>(W1, w1t);
    k_wt   <<<D, 256, 0, stream>>>(W2, w2t);
    k_count<<<(N_EDGES + 255) / 256, 256, 0, stream>>>(coli, cnt);
    k_edge <<<(N_EDGES + 63) / 64, 256, 0, stream>>>(xb, ea, w1t, b1, rowi, coli, agg);
    k_node <<<(N_NODES + 63) / 64, 256, 0, stream>>>(xb, agg, cnt, w2t, b2, out);
}

// Round 2
// 555.043 us; speedup vs baseline: 1.1054x; 1.1054x over previous
//
#include <hip/hip_runtime.h>

#define N_NODES 50000
#define N_EDGES 500000
#define D 256
#define TWO_D 512

typedef __attribute__((ext_vector_type(8))) __bf16 bf16x8;
typedef __attribute__((ext_vector_type(4))) float f32x4;
typedef unsigned short ushort_t;

__device__ __forceinline__ unsigned short f2bf(float f) {
    unsigned int u = __builtin_bit_cast(unsigned int, f);
    u += 0x7FFFu + ((u >> 16) & 1u);   // round-to-nearest-even
    return (unsigned short)(u >> 16);
}
__device__ __forceinline__ unsigned int pk2(float lo, float hi) {
    return (unsigned int)f2bf(lo) | ((unsigned int)f2bf(hi) << 16);
}
__device__ __forceinline__ float bf2f(ushort_t u) {
    return __builtin_bit_cast(float, ((unsigned int)u) << 16);
}

// ---------------- prep kernels ----------------

__global__ void k_zero(float* __restrict__ p, int n4) {
    int i = blockIdx.x * blockDim.x + threadIdx.x;
    if (i < n4) ((float4*)p)[i] = make_float4(0.f, 0.f, 0.f, 0.f);
}

__global__ void k_cvt_x(const float* __restrict__ x, ushort_t* __restrict__ xb, int n8) {
    int i = blockIdx.x * blockDim.x + threadIdx.x;
    if (i < n8) {
        const float4* s = (const float4*)(x + (size_t)i * 8);
        float4 a = s[0], b = s[1];
        uint4 o;
        o.x = pk2(a.x, a.y); o.y = pk2(a.z, a.w);
        o.z = pk2(b.x, b.y); o.w = pk2(b.z, b.w);
        *(uint4*)(xb + (size_t)i * 8) = o;
    }
}

// W [TWO_D][D] f32  ->  Wt [D][TWO_D] bf16
__global__ void k_wt(const float* __restrict__ w, ushort_t* __restrict__ wt) {
    int n = blockIdx.x;
    for (int k = threadIdx.x; k < TWO_D; k += blockDim.x)
        wt[(size_t)n * TWO_D + k] = f2bf(w[(size_t)k * D + n]);
}

__global__ void k_count_i(const int* __restrict__ coli, int* __restrict__ cnt) {
    int e = blockIdx.x * blockDim.x + threadIdx.x;
    if (e < N_EDGES) atomicAdd(&cnt[coli[e]], 1);
}

__global__ void k_count_f(const int* __restrict__ coli, float* __restrict__ cnt) {
    int e = blockIdx.x * blockDim.x + threadIdx.x;
    if (e < N_EDGES) atomicAdd(&cnt[coli[e]], 1.0f);
}

// ---------------- CSR build: 3-kernel scan + bucket fill ----------------

__device__ __forceinline__ int iscan_block(int v, int tid) {
    // inclusive scan across 256 threads (4 waves of 64)
    int lane = tid & 63, wv = tid >> 6;
    int s = v;
    #pragma unroll
    for (int off = 1; off < 64; off <<= 1) {
        int t = __shfl_up(s, off, 64);
        if (lane >= off) s += t;
    }
    __shared__ int wsum[4];
    if (lane == 63) wsum[wv] = s;
    __syncthreads();
    #pragma unroll
    for (int w = 0; w < 3; ++w)
        if (wv > w) s += wsum[w];
    return s;
}

__global__ void k_scan_a(const int* __restrict__ cnt, int* __restrict__ rowptr,
                         int* __restrict__ bsum) {
    int i = blockIdx.x * 256 + threadIdx.x;
    int v = (i < N_NODES) ? cnt[i] : 0;
    int s = iscan_block(v, threadIdx.x);
    if (i < N_NODES) rowptr[i] = s - v;          // block-local exclusive
    if (threadIdx.x == 255) bsum[blockIdx.x] = s; // block total
}

__global__ void k_scan_b(int* __restrict__ bsum, int nb) {
    int i = threadIdx.x;
    int v = (i < nb) ? bsum[i] : 0;
    int s = iscan_block(v, i);
    if (i < nb) bsum[i] = s - v;                  // exclusive
}

__global__ void k_scan_c(int* __restrict__ rowptr, const int* __restrict__ bsum,
                         int* __restrict__ cursor) {
    int i = blockIdx.x * 256 + threadIdx.x;
    if (i < N_NODES) {
        int r = rowptr[i] + bsum[blockIdx.x];
        rowptr[i] = r;
        cursor[i] = r;
    }
    if (i == 0) rowptr[N_NODES] = N_EDGES;
}

__global__ void k_fill(const int* __restrict__ coli, int* __restrict__ cursor,
                       int* __restrict__ elist) {
    int e = blockIdx.x * blockDim.x + threadIdx.x;
    if (e < N_EDGES) {
        int p = atomicAdd(&cursor[coli[e]], 1);
        elist[p] = e;
    }
}

// ---------------- edge GEMM ----------------
// C[e][n] = relu( concat(x[row[e]], ea[e]) @ W1 + b1 )
// CSR=true : store bf16 h row
// CSR=false: atomicAdd into agg[col[e]] (skip zeros)
template<bool CSR>
__global__ __launch_bounds__(256) void k_edge_t(
    const ushort_t* __restrict__ xb, const float* __restrict__ ea,
    const ushort_t* __restrict__ w1t, const float* __restrict__ b1,
    const int* __restrict__ rowi, const int* __restrict__ coli,
    ushort_t* __restrict__ h, float* __restrict__ agg)
{
    __shared__ __align__(16) ushort_t As[64 * 64];
    __shared__ __align__(16) ushort_t Bs[256 * 64];
    const int tid = threadIdx.x;
    const int wave = tid >> 6, lane = tid & 63;
    const int lr = lane & 15, lh = lane >> 4;
    const int e0 = blockIdx.x * 64;

    const int sm = tid >> 2;
    const int sc = (tid & 3) << 4;
    int es = e0 + sm; if (es >= N_EDGES) es = N_EDGES - 1;
    const int srow = rowi[es];
    const ushort_t* xrow  = xb + (size_t)srow * D;
    const float*    earow = ea + (size_t)es * D;
    const ushort_t* wrow  = w1t + (size_t)tid * TWO_D;
    const int swA = (sm & 7) << 3;
    const int swB = (tid & 7) << 3;

    f32x4 acc[4][4];
    #pragma unroll
    for (int i = 0; i < 4; ++i)
        #pragma unroll
        for (int j = 0; j < 4; ++j)
            acc[i][j] = (f32x4){0.f, 0.f, 0.f, 0.f};

    for (int kk = 0; kk < 8; ++kk) {
        const int k0 = kk << 6;
        uint4 av0, av1;
        if (kk < 4) {
            const uint4* s = (const uint4*)(xrow + k0 + sc);
            av0 = s[0]; av1 = s[1];
        } else {
            const float4* s = (const float4*)(earow + (k0 - D) + sc);
            float4 f0 = s[0], f1 = s[1], f2 = s[2], f3 = s[3];
            av0.x = pk2(f0.x, f0.y); av0.y = pk2(f0.z, f0.w);
            av0.z = pk2(f1.x, f1.y); av0.w = pk2(f1.z, f1.w);
            av1.x = pk2(f2.x, f2.y); av1.y = pk2(f2.z, f2.w);
            av1.z = pk2(f3.x, f3.y); av1.w = pk2(f3.z, f3.w);
        }
        const uint4* wsv = (const uint4*)(wrow + k0);
        uint4 w0 = wsv[0], w1 = wsv[1], w2 = wsv[2], w3 = wsv[3];
        uint4 w4 = wsv[4], w5 = wsv[5], w6 = wsv[6], w7 = wsv[7];

        __syncthreads();
        *(uint4*)&As[sm * 64 + ( sc      ^ swA)] = av0;
        *(uint4*)&As[sm * 64 + ((sc + 8) ^ swA)] = av1;
        {
            const int base = tid * 64;
            *(uint4*)&Bs[base + ( 0 ^ swB)] = w0;
            *(uint4*)&Bs[base + ( 8 ^ swB)] = w1;
            *(uint4*)&Bs[base + (16 ^ swB)] = w2;
            *(uint4*)&Bs[base + (24 ^ swB)] = w3;
            *(uint4*)&Bs[base + (32 ^ swB)] = w4;
            *(uint4*)&Bs[base + (40 ^ swB)] = w5;
            *(uint4*)&Bs[base + (48 ^ swB)] = w6;
            *(uint4*)&Bs[base + (56 ^ swB)] = w7;
        }
        __syncthreads();

        #pragma unroll
        for (int kh = 0; kh < 2; ++kh) {
            const int kb = kh * 32 + lh * 8;
            bf16x8 af[4], bfr[4];
            #pragma unroll
            for (int i = 0; i < 4; ++i) {
                int m = i * 16 + lr;
                af[i] = *(const bf16x8*)&As[m * 64 + (kb ^ ((m & 7) << 3))];
            }
            #pragma unroll
            for (int j = 0; j < 4; ++j) {
                int n = wave * 64 + j * 16 + lr;
                bfr[j] = *(const bf16x8*)&Bs[n * 64 + (kb ^ ((n & 7) << 3))];
            }
            #pragma unroll
            for (int i = 0; i < 4; ++i)
                #pragma unroll
                for (int j = 0; j < 4; ++j)
                    acc[i][j] = __builtin_amdgcn_mfma_f32_16x16x32_bf16(af[i], bfr[j], acc[i][j], 0, 0, 0);
        }
    }

    float bv[4];
    #pragma unroll
    for (int j = 0; j < 4; ++j) bv[j] = b1[wave * 64 + j * 16 + lr];
    #pragma unroll
    for (int i = 0; i < 4; ++i) {
        #pragma unroll
        for (int r = 0; r < 4; ++r) {
            int m = i * 16 + lh * 4 + r;
            int e = e0 + m;
            if (e < N_EDGES) {
                if constexpr (CSR) {
                    ushort_t* hrow = h + (size_t)e * D + wave * 64 + lr;
                    #pragma unroll
                    for (int j = 0; j < 4; ++j) {
                        float v = acc[i][j][r] + bv[j];
                        hrow[j * 16] = f2bf(v > 0.f ? v : 0.f);
                    }
                } else {
                    float* arow = agg + (size_t)coli[e] * D;
                    #pragma unroll
                    for (int j = 0; j < 4; ++j) {
                        float v = acc[i][j][r] + bv[j];
                        if (v > 0.f) atomicAdd(&arow[wave * 64 + j * 16 + lr], v);
                    }
                }
            }
        }
    }
}

// ---------------- aggregation (CSR path): mean of h rows per node ----------------
__global__ __launch_bounds__(256) void k_agg(
    const ushort_t* __restrict__ h, const int* __restrict__ rowptr,
    const int* __restrict__ elist, ushort_t* __restrict__ aggb)
{
    int node = blockIdx.x * 4 + (threadIdx.x >> 6);
    if (node >= N_NODES) return;
    int lane = threadIdx.x & 63;
    int beg = rowptr[node], end = rowptr[node + 1];
    float a0 = 0.f, a1 = 0.f, a2 = 0.f, a3 = 0.f;
    int p = beg;
    int e_nxt = (p < end) ? elist[p] : 0;
    while (p < end) {
        int e = e_nxt;
        if (p + 1 < end) e_nxt = elist[p + 1];
        ushort4 u = *(const ushort4*)(h + (size_t)e * D + lane * 4);
        a0 += bf2f(u.x); a1 += bf2f(u.y); a2 += bf2f(u.z); a3 += bf2f(u.w);
        ++p;
    }
    float inv = 1.0f / fmaxf((float)(end - beg), 1.0f);
    ushort4 o;
    o.x = f2bf(a0 * inv); o.y = f2bf(a1 * inv);
    o.z = f2bf(a2 * inv); o.w = f2bf(a3 * inv);
    *(ushort4*)(aggb + (size_t)node * D + lane * 4) = o;
}

// ---------------- node GEMM ----------------
// out[i][n] = relu( concat(x[i], agg[i]) @ W2 + b2 )
// CSR=true : aggb is bf16, already divided by count
// CSR=false: aggf is f32 sums, divide by cnt
template<bool CSR>
__global__ __launch_bounds__(256) void k_node_t(
    const ushort_t* __restrict__ xb, const ushort_t* __restrict__ aggb,
    const float* __restrict__ aggf, const float* __restrict__ cnt,
    const ushort_t* __restrict__ w2t, const float* __restrict__ b2,
    float* __restrict__ out)
{
    __shared__ __align__(16) ushort_t As[64 * 64];
    __shared__ __align__(16) ushort_t Bs[256 * 64];
    const int tid = threadIdx.x;
    const int wave = tid >> 6, lane = tid & 63;
    const int lr = lane & 15, lh = lane >> 4;
    const int n0 = blockIdx.x * 64;

    const int sm = tid >> 2;
    const int sc = (tid & 3) << 4;
    int ns = n0 + sm; if (ns >= N_NODES) ns = N_NODES - 1;
    const ushort_t* xrow = xb + (size_t)ns * D;
    const ushort_t* abrow = CSR ? (aggb + (size_t)ns * D) : nullptr;
    const float*    afrow = CSR ? nullptr : (aggf + (size_t)ns * D);
    const float     ic    = CSR ? 1.0f : (1.0f / fmaxf(cnt[ns], 1.0f));
    const ushort_t* wrow = w2t + (size_t)tid * TWO_D;
    const int swA = (sm & 7) << 3;
    const int swB = (tid & 7) << 3;

    f32x4 acc[4][4];
    #pragma unroll
    for (int i = 0; i < 4; ++i)
        #pragma unroll
        for (int j = 0; j < 4; ++j)
            acc[i][j] = (f32x4){0.f, 0.f, 0.f, 0.f};

    for (int kk = 0; kk < 8; ++kk) {
        const int k0 = kk << 6;
        uint4 av0, av1;
        if (kk < 4) {
            const uint4* s = (const uint4*)(xrow + k0 + sc);
            av0 = s[0]; av1 = s[1];
        } else if constexpr (CSR) {
            const uint4* s = (const uint4*)(abrow + (k0 - D) + sc);
            av0 = s[0]; av1 = s[1];
        } else {
            const float4* s = (const float4*)(afrow + (k0 - D) + sc);
            float4 f0 = s[0], f1 = s[1], f2 = s[2], f3 = s[3];
            f0.x *= ic; f0.y *= ic; f0.z *= ic; f0.w *= ic;
            f1.x *= ic; f1.y *= ic; f1.z *= ic; f1.w *= ic;
            f2.x *= ic; f2.y *= ic; f2.z *= ic; f2.w *= ic;
            f3.x *= ic; f3.y *= ic; f3.z *= ic; f3.w *= ic;
            av0.x = pk2(f0.x, f0.y); av0.y = pk2(f0.z, f0.w);
            av0.z = pk2(f1.x, f1.y); av0.w = pk2(f1.z, f1.w);
            av1.x = pk2(f2.x, f2.y); av1.y = pk2(f2.z, f2.w);
            av1.z = pk2(f3.x, f3.y); av1.w = pk2(f3.z, f3.w);
        }
        const uint4* wsv = (const uint4*)(wrow + k0);
        uint4 w0 = wsv[0], w1 = wsv[1], w2 = wsv[2], w3 = wsv[3];
        uint4 w4 = wsv[4], w5 = wsv[5], w6 = wsv[6], w7 = wsv[7];

        __syncthreads();
        *(uint4*)&As[sm * 64 + ( sc      ^ swA)] = av0;
        *(uint4*)&As[sm * 64 + ((sc + 8) ^ swA)] = av1;
        {
            const int base = tid * 64;
            *(uint4*)&Bs[base + ( 0 ^ swB)] = w0;
            *(uint4*)&Bs[base + ( 8 ^ swB)] = w1;
            *(uint4*)&Bs[base + (16 ^ swB)] = w2;
            *(uint4*)&Bs[base + (24 ^ swB)] = w3;
            *(uint4*)&Bs[base + (32 ^ swB)] = w4;
            *(uint4*)&Bs[base + (40 ^ swB)] = w5;
            *(uint4*)&Bs[base + (48 ^ swB)] = w6;
            *(uint4*)&Bs[base + (56 ^ swB)] = w7;
        }
        __syncthreads();

        #pragma unroll
        for (int kh = 0; kh < 2; ++kh) {
            const int kb = kh * 32 + lh * 8;
            bf16x8 af[4], bfr[4];
            #pragma unroll
            for (int i = 0; i < 4; ++i) {
                int m = i * 16 + lr;
                af[i] = *(const bf16x8*)&As[m * 64 + (kb ^ ((m & 7) << 3))];
            }
            #pragma unroll
            for (int j = 0; j < 4; ++j) {
                int n = wave * 64 + j * 16 + lr;
                bfr[j] = *(const bf16x8*)&Bs[n * 64 + (kb ^ ((n & 7) << 3))];
            }
            #pragma unroll
            for (int i = 0; i < 4; ++i)
                #pragma unroll
                for (int j = 0; j < 4; ++j)
                    acc[i][j] = __builtin_amdgcn_mfma_f32_16x16x32_bf16(af[i], bfr[j], acc[i][j], 0, 0, 0);
        }
    }

    float bv[4];
    #pragma unroll
    for (int j = 0; j < 4; ++j) bv[j] = b2[wave * 64 + j * 16 + lr];
    #pragma unroll
    for (int i = 0; i < 4; ++i) {
        #pragma unroll
        for (int r = 0; r < 4; ++r) {
            int m = i * 16 + lh * 4 + r;
            int node = n0 + m;
            if (node < N_NODES) {
                float* orow = out + (size_t)node * D;
                #pragma unroll
                for (int j = 0; j < 4; ++j) {
                    float v = acc[i][j][r] + bv[j];
                    orow[wave * 64 + j * 16 + lr] = v > 0.f ? v : 0.f;
                }
            }
        }
    }
}

// ---------------- launch ----------------

extern "C" void kernel_launch(void* const* d_in, const int* in_sizes, int n_in,
                              void* d_out, int out_size, void* d_ws, size_t ws_size,
                              hipStream_t stream)
{
    const float* x  = (const float*)d_in[0];
    const int*   ei = (const int*)d_in[1];      // [2*E] int32: rows then cols
    const float* ea = (const float*)d_in[2];
    const float* W1 = (const float*)d_in[5];
    const float* b1 = (const float*)d_in[6];
    const float* W2 = (const float*)d_in[7];
    const float* b2 = (const float*)d_in[8];
    float* out = (float*)d_out;

    const int* rowi = ei;
    const int* coli = ei + N_EDGES;
    char* ws = (char*)d_ws;

    size_t off = 0;
    auto take = [&](size_t bytes) {
        char* p = ws + off;
        off = (off + bytes + 255) & ~(size_t)255;
        return p;
    };

    // shared prep regions
    ushort_t* xb  = (ushort_t*)take((size_t)N_NODES * D * 2);
    ushort_t* w1t = (ushort_t*)take((size_t)D * TWO_D * 2);
    ushort_t* w2t = (ushort_t*)take((size_t)D * TWO_D * 2);
    size_t off_common = off;

    // CSR-path regions
    ushort_t* aggb   = (ushort_t*)take((size_t)N_NODES * D * 2);
    ushort_t* h      = (ushort_t*)take((size_t)N_EDGES * D * 2);
    int*      cnti   = (int*)take(50016 * 4);
    int*      rowptr = (int*)take(50016 * 4);
    int*      cursor = (int*)take(50016 * 4);
    int*      bsum   = (int*)take(256 * 4);
    int*      elist  = (int*)take((size_t)N_EDGES * 4);
    const bool use_csr = (off <= ws_size);

    k_cvt_x<<<(N_NODES * D / 8 + 255) / 256, 256, 0, stream>>>(x, xb, N_NODES * D / 8);
    k_wt   <<<D, 256, 0, stream>>>(W1, w1t);
    k_wt   <<<D, 256, 0, stream>>>(W2, w2t);

    if (use_csr) {
        const int NB = (N_NODES + 255) / 256;   // 196
        k_zero   <<<49, 256, 0, stream>>>((float*)cnti, 50016 / 4);
        k_count_i<<<(N_EDGES + 255) / 256, 256, 0, stream>>>(coli, cnti);
        k_scan_a <<<NB, 256, 0, stream>>>(cnti, rowptr, bsum);
        k_scan_b <<<1, 256, 0, stream>>>(bsum, NB);
        k_scan_c <<<NB, 256, 0, stream>>>(rowptr, bsum, cursor);
        k_fill   <<<(N_EDGES + 255) / 256, 256, 0, stream>>>(coli, cursor, elist);
        k_edge_t<true><<<(N_EDGES + 63) / 64, 256, 0, stream>>>(
            xb, ea, w1t, b1, rowi, coli, h, nullptr);
        k_agg    <<<(N_NODES + 3) / 4, 256, 0, stream>>>(h, rowptr, elist, aggb);
        k_node_t<true><<<(N_NODES + 63) / 64, 256, 0, stream>>>(
            xb, aggb, nullptr, nullptr, w2t, b2, out);
    } else {
        // fallback: round-1 atomic path (ws too small for h buffer)
        off = off_common;
        float* aggf = (float*)take((size_t)(N_NODES * D + 50048) * 4);
        float* cntf = aggf + (size_t)N_NODES * D;
        const int zf4 = (N_NODES * D + 50048) / 4;
        k_zero   <<<(zf4 + 255) / 256, 256, 0, stream>>>(aggf, zf4);
        k_count_f<<<(N_EDGES + 255) / 256, 256, 0, stream>>>(coli, cntf);
        k_edge_t<false><<<(N_EDGES + 63) / 64, 256, 0, stream>>>(
            xb, ea, w1t, b1, rowi, coli, nullptr, aggf);
        k_node_t<false><<<(N_NODES + 63) / 64, 256, 0, stream>>>(
            xb, nullptr, aggf, cntf, w2t, b2, out);
    }
}